// Round 2
// baseline (669.162 us; speedup 1.0000x reference)
//
#include <hip/hip_runtime.h>
#include <hip/hip_bf16.h>

typedef __attribute__((ext_vector_type(8))) short short8;
typedef __attribute__((ext_vector_type(4))) short short4v;
typedef __attribute__((ext_vector_type(4))) float f32x4;

#define Dk 1024
#define TT 2048
#define BB 8
#define MROWS (BB * TT)   // 16384

#if defined(__has_builtin)
#if __has_builtin(__builtin_amdgcn_rcpf)
#define FAST_RCP(x) __builtin_amdgcn_rcpf(x)
#endif
#endif
#ifndef FAST_RCP
#define FAST_RCP(x) (1.f / (x))
#endif

__device__ __forceinline__ void gload_lds16(const void* g, void* l) {
    __builtin_amdgcn_global_load_lds(
        (const __attribute__((address_space(1))) void*)g,
        (__attribute__((address_space(3))) void*)l, 16, 0, 0);
}

__device__ __forceinline__ float sigmoidf_fast(float x) {
    return FAST_RCP(1.f + __expf(-x));
}

// fp32 -> bf16 conversion, 4 elems/thread, n % 1024 == 0
__global__ __launch_bounds__(256)
void cvt_f32_bf16(const float* __restrict__ in, __hip_bfloat16* __restrict__ out, int n) {
    const int i = (blockIdx.x * 256 + threadIdx.x) * 4;
    if (i >= n) return;
    const float4 v = *(const float4*)(in + i);
    __hip_bfloat16 tmp[4];
    tmp[0] = __float2bfloat16(v.x);
    tmp[1] = __float2bfloat16(v.y);
    tmp[2] = __float2bfloat16(v.z);
    tmp[3] = __float2bfloat16(v.w);
    *(short4v*)(out + i) = *(const short4v*)tmp;
}

// C = epi(A * B^T). A: [M x 1024] bf16 rm, Bw: [1024 x 1024] bf16 rm ([e][d]).
// EPI: 0 silu->bf16 | 1 plain->f32 | 2 tanh(x+bias)->f32 | 4 plain->bf16 | 5 tanh(x+bias)->bf16
template<int EPI>
__global__ __launch_bounds__(256)
void gemm_bt(const __hip_bfloat16* __restrict__ A,
             const __hip_bfloat16* __restrict__ Bw,
             const float* __restrict__ bias,
             void* __restrict__ CoutV)
{
    __shared__ __hip_bfloat16 sA[128 * 32];
    __shared__ __hip_bfloat16 sB[128 * 32];

    const int tid  = threadIdx.x;
    const int tn   = blockIdx.x & 7;
    const int tm   = blockIdx.x >> 3;
    const int lane = tid & 63;
    const int w    = tid >> 6;
    const int wr   = (w >> 1) * 64;
    const int wc   = (w & 1) * 64;
    const int l15  = lane & 15;
    const int lq   = lane >> 4;

    f32x4 acc[4][4];
#pragma unroll
    for (int m = 0; m < 4; ++m)
#pragma unroll
        for (int n = 0; n < 4; ++n)
            acc[m][n] = (f32x4){0.f, 0.f, 0.f, 0.f};

    const size_t baseA = (size_t)(tm * 128) * Dk;
    const size_t baseB = (size_t)(tn * 128) * Dk;

    for (int k0 = 0; k0 < Dk; k0 += 32) {
#pragma unroll
        for (int i = 0; i < 2; ++i) {
            const int li  = i * 256 + tid;
            const int row = li >> 2;
            const int cb  = li & 3;
            gload_lds16(A  + baseA + (size_t)row * Dk + k0 + cb * 8,
                        (char*)sA + li * 16);
            gload_lds16(Bw + baseB + (size_t)row * Dk + k0 + cb * 8,
                        (char*)sB + li * 16);
        }
        __syncthreads();

        short8 af[4], bfr[4];
#pragma unroll
        for (int m = 0; m < 4; ++m)
            af[m] = *(const short8*)(sA + (wr + m * 16 + l15) * 32 + lq * 8);
#pragma unroll
        for (int n = 0; n < 4; ++n)
            bfr[n] = *(const short8*)(sB + (wc + n * 16 + l15) * 32 + lq * 8);

#pragma unroll
        for (int m = 0; m < 4; ++m)
#pragma unroll
            for (int n = 0; n < 4; ++n)
                acc[m][n] = __builtin_amdgcn_mfma_f32_16x16x32_bf16(
                    af[m], bfr[n], acc[m][n], 0, 0, 0);
        __syncthreads();
    }

#pragma unroll
    for (int m = 0; m < 4; ++m) {
#pragma unroll
        for (int n = 0; n < 4; ++n) {
            const int col = tn * 128 + wc + n * 16 + l15;
            float bv = 0.f;
            if (EPI == 2 || EPI == 5) bv = bias[col];
#pragma unroll
            for (int j = 0; j < 4; ++j) {
                const int rowl = wr + m * 16 + lq * 4 + j;
                const size_t idx = (size_t)(tm * 128 + rowl) * Dk + col;
                const float xv = acc[m][n][j];
                if constexpr (EPI == 0) {
                    ((__hip_bfloat16*)CoutV)[idx] = __float2bfloat16(xv * sigmoidf_fast(xv));
                } else if constexpr (EPI == 1) {
                    ((float*)CoutV)[idx] = xv;
                } else if constexpr (EPI == 2) {
                    ((float*)CoutV)[idx] = tanhf(xv + bv);
                } else if constexpr (EPI == 4) {
                    ((__hip_bfloat16*)CoutV)[idx] = __float2bfloat16(xv);
                } else {
                    ((__hip_bfloat16*)CoutV)[idx] = __float2bfloat16(tanhf(xv + bv));
                }
            }
        }
    }
}

// Sequential scan. One thread per (b,d) chain. E = exp(-(ax+b_alpha)) precomputed
// off the critical path; per-step chain: mul -> exp -> fma -> rcp -> fma.
template<bool INF32>
__global__ __launch_bounds__(64)
void scan_kernel(const void* __restrict__ axp, const void* __restrict__ vvp,
                 const float* __restrict__ h0,
                 const float* __restrict__ dal, const float* __restrict__ bal,
                 __hip_bfloat16* __restrict__ cell, float* __restrict__ hfin)
{
    const int g = blockIdx.x * 64 + threadIdx.x;   // 0..8191
    const int b = g >> 10;
    const int d = g & 1023;

    float h = h0[g];
    const float ba  = bal[d];
    const float nda = -dal[d];
    const size_t base = (size_t)b * TT * Dk + d;

    const float* axf = (const float*)axp;
    const float* vvf = (const float*)vvp;
    const __hip_bfloat16* axh = (const __hip_bfloat16*)axp;
    const __hip_bfloat16* vvh = (const __hip_bfloat16*)vvp;

    constexpr int NT = 32;
    constexpr int NBLK = TT / NT;   // 64
    float E0[NT], V0[NT], E1[NT], V1[NT];

#pragma unroll
    for (int i = 0; i < NT; ++i) {
        const size_t o = base + (size_t)i * Dk;
        const float a = INF32 ? axf[o] : __bfloat162float(axh[o]);
        E0[i] = __expf(-(a + ba));
        V0[i] = INF32 ? vvf[o] : __bfloat162float(vvh[o]);
    }

    for (int blk = 0; blk < NBLK; blk += 2) {
        {
            const size_t off = base + (size_t)(blk + 1) * NT * Dk;
#pragma unroll
            for (int i = 0; i < NT; ++i) {
                const size_t o = off + (size_t)i * Dk;
                const float a = INF32 ? axf[o] : __bfloat162float(axh[o]);
                E1[i] = __expf(-(a + ba));
                V1[i] = INF32 ? vvf[o] : __bfloat162float(vvh[o]);
            }
        }
#pragma unroll
        for (int i = 0; i < NT; ++i) {
            const float u   = __expf(nda * h);
            const float al  = FAST_RCP(fmaf(E0[i], u, 1.f));
            h = fmaf(al, h - V0[i], V0[i]);
            const float s = sigmoidf_fast(h);
            cell[base + (size_t)(blk * NT + i) * Dk] = __float2bfloat16(h * h * s);
        }
        if (blk + 2 < NBLK) {
            const size_t off = base + (size_t)(blk + 2) * NT * Dk;
#pragma unroll
            for (int i = 0; i < NT; ++i) {
                const size_t o = off + (size_t)i * Dk;
                const float a = INF32 ? axf[o] : __bfloat162float(axh[o]);
                E0[i] = __expf(-(a + ba));
                V0[i] = INF32 ? vvf[o] : __bfloat162float(vvh[o]);
            }
        }
#pragma unroll
        for (int i = 0; i < NT; ++i) {
            const float u   = __expf(nda * h);
            const float al  = FAST_RCP(fmaf(E1[i], u, 1.f));
            h = fmaf(al, h - V1[i], V1[i]);
            const float s = sigmoidf_fast(h);
            cell[base + (size_t)((blk + 1) * NT + i) * Dk] = __float2bfloat16(h * h * s);
        }
    }

    hfin[g] = h;
}

extern "C" void kernel_launch(void* const* d_in, const int* in_sizes, int n_in,
                              void* d_out, int out_size, void* d_ws, size_t ws_size,
                              hipStream_t stream)
{
    const float* x     = (const float*)d_in[0];
    const float* h0    = (const float*)d_in[1];
    const float* W_in  = (const float*)d_in[2];
    const float* W_al  = (const float*)d_in[3];
    const float* d_al  = (const float*)d_in[4];
    const float* b_al  = (const float*)d_in[5];
    const float* W_x   = (const float*)d_in[6];
    const float* b_v   = (const float*)d_in[7];
    const float* W_out = (const float*)d_in[8];

    float* out  = (float*)d_out;
    float* hfin = out + (size_t)MROWS * Dk;

    char* ws = (char*)d_ws;
    const size_t bfBuf = (size_t)MROWS * Dk * sizeof(__hip_bfloat16);  // 33.5 MB
    const size_t wBuf  = (size_t)Dk * Dk * sizeof(__hip_bfloat16);     // 2 MB
    const size_t f32Buf = (size_t)MROWS * Dk * sizeof(float);          // 67 MB

    __hip_bfloat16* xb    = (__hip_bfloat16*)(ws);
    __hip_bfloat16* Winb  = (__hip_bfloat16*)(ws + bfBuf);
    __hip_bfloat16* Walb  = (__hip_bfloat16*)(ws + bfBuf + wBuf);
    __hip_bfloat16* Wxb   = (__hip_bfloat16*)(ws + bfBuf + 2 * wBuf);
    __hip_bfloat16* Woutb = (__hip_bfloat16*)(ws + bfBuf + 3 * wBuf);
    char* rest = ws + bfBuf + 4 * wBuf;
    __hip_bfloat16* xproj = (__hip_bfloat16*)rest;
    __hip_bfloat16* cellb = xb;  // x dead after GEMM1

    const bool useF32 = ws_size >= bfBuf + 4 * wBuf + bfBuf + 2 * f32Buf;
    void* axb = (void*)(rest + bfBuf);
    void* vb  = useF32 ? (void*)(rest + bfBuf + f32Buf)
                       : (void*)(rest + bfBuf + bfBuf);

    dim3 blk(256);
    // fp32 -> bf16 conversions
    cvt_f32_bf16<<<dim3(MROWS * Dk / 1024), blk, 0, stream>>>(x, xb, MROWS * Dk);
    cvt_f32_bf16<<<dim3(Dk * Dk / 1024), blk, 0, stream>>>(W_in,  Winb,  Dk * Dk);
    cvt_f32_bf16<<<dim3(Dk * Dk / 1024), blk, 0, stream>>>(W_al,  Walb,  Dk * Dk);
    cvt_f32_bf16<<<dim3(Dk * Dk / 1024), blk, 0, stream>>>(W_x,   Wxb,   Dk * Dk);
    cvt_f32_bf16<<<dim3(Dk * Dk / 1024), blk, 0, stream>>>(W_out, Woutb, Dk * Dk);

    dim3 grid(1024);
    gemm_bt<0><<<grid, blk, 0, stream>>>(xb, Winb, nullptr, xproj);
    if (useF32) {
        gemm_bt<1><<<grid, blk, 0, stream>>>(xproj, Walb, nullptr, axb);
        gemm_bt<2><<<grid, blk, 0, stream>>>(xproj, Wxb,  b_v,    vb);
        scan_kernel<true><<<dim3(128), dim3(64), 0, stream>>>(axb, vb, h0, d_al, b_al, cellb, hfin);
    } else {
        gemm_bt<4><<<grid, blk, 0, stream>>>(xproj, Walb, nullptr, axb);
        gemm_bt<5><<<grid, blk, 0, stream>>>(xproj, Wxb,  b_v,    vb);
        scan_kernel<false><<<dim3(128), dim3(64), 0, stream>>>(axb, vb, h0, d_al, b_al, cellb, hfin);
    }
    gemm_bt<1><<<grid, blk, 0, stream>>>(cellb, Woutb, nullptr, out);
}

// Round 3
// 412.470 us; speedup vs baseline: 1.6223x; 1.6223x over previous
//
#include <hip/hip_runtime.h>
#include <hip/hip_bf16.h>

typedef __attribute__((ext_vector_type(8))) short short8;
typedef __attribute__((ext_vector_type(4))) short short4v;
typedef __attribute__((ext_vector_type(4))) float f32x4;

#define Dk 1024
#define TT 2048
#define BB 8
#define MROWS (BB * TT)   // 16384

#if defined(__has_builtin)
#if __has_builtin(__builtin_amdgcn_rcpf)
#define FAST_RCP(x) __builtin_amdgcn_rcpf(x)
#endif
#endif
#ifndef FAST_RCP
#define FAST_RCP(x) (1.f / (x))
#endif

__device__ __forceinline__ void gload_lds16(const void* g, void* l) {
    __builtin_amdgcn_global_load_lds(
        (const __attribute__((address_space(1))) void*)g,
        (__attribute__((address_space(3))) void*)l, 16, 0, 0);
}

__device__ __forceinline__ float sigmoidf_fast(float x) {
    return FAST_RCP(1.f + __expf(-x));
}

// fp32 -> bf16 conversion, 4 elems/thread, n % 1024 == 0
__global__ __launch_bounds__(256)
void cvt_f32_bf16(const float* __restrict__ in, __hip_bfloat16* __restrict__ out, int n) {
    const int i = (blockIdx.x * 256 + threadIdx.x) * 4;
    if (i >= n) return;
    const float4 v = *(const float4*)(in + i);
    __hip_bfloat16 tmp[4];
    tmp[0] = __float2bfloat16(v.x);
    tmp[1] = __float2bfloat16(v.y);
    tmp[2] = __float2bfloat16(v.z);
    tmp[3] = __float2bfloat16(v.w);
    *(short4v*)(out + i) = *(const short4v*)tmp;
}

// C = epi(A * B^T). A: [M x 1024] bf16 rm, Bw: [1024 x 1024] bf16 rm ([e][d]).
// EPI: 0 silu->bf16 | 1 plain->f32 | 4 plain->bf16 | 5 tanh(x+bias)->bf16
template<int EPI>
__global__ __launch_bounds__(256)
void gemm_bt(const __hip_bfloat16* __restrict__ A,
             const __hip_bfloat16* __restrict__ Bw,
             const float* __restrict__ bias,
             void* __restrict__ CoutV)
{
    __shared__ __hip_bfloat16 sA[128 * 32];
    __shared__ __hip_bfloat16 sB[128 * 32];

    const int tid  = threadIdx.x;
    const int tn   = blockIdx.x & 7;
    const int tm   = blockIdx.x >> 3;
    const int lane = tid & 63;
    const int w    = tid >> 6;
    const int wr   = (w >> 1) * 64;
    const int wc   = (w & 1) * 64;
    const int l15  = lane & 15;
    const int lq   = lane >> 4;

    f32x4 acc[4][4];
#pragma unroll
    for (int m = 0; m < 4; ++m)
#pragma unroll
        for (int n = 0; n < 4; ++n)
            acc[m][n] = (f32x4){0.f, 0.f, 0.f, 0.f};

    const size_t baseA = (size_t)(tm * 128) * Dk;
    const size_t baseB = (size_t)(tn * 128) * Dk;

    for (int k0 = 0; k0 < Dk; k0 += 32) {
#pragma unroll
        for (int i = 0; i < 2; ++i) {
            const int li  = i * 256 + tid;
            const int row = li >> 2;
            const int cb  = li & 3;
            gload_lds16(A  + baseA + (size_t)row * Dk + k0 + cb * 8,
                        (char*)sA + li * 16);
            gload_lds16(Bw + baseB + (size_t)row * Dk + k0 + cb * 8,
                        (char*)sB + li * 16);
        }
        __syncthreads();

        short8 af[4], bfr[4];
#pragma unroll
        for (int m = 0; m < 4; ++m)
            af[m] = *(const short8*)(sA + (wr + m * 16 + l15) * 32 + lq * 8);
#pragma unroll
        for (int n = 0; n < 4; ++n)
            bfr[n] = *(const short8*)(sB + (wc + n * 16 + l15) * 32 + lq * 8);

#pragma unroll
        for (int m = 0; m < 4; ++m)
#pragma unroll
            for (int n = 0; n < 4; ++n)
                acc[m][n] = __builtin_amdgcn_mfma_f32_16x16x32_bf16(
                    af[m], bfr[n], acc[m][n], 0, 0, 0);
        __syncthreads();
    }

#pragma unroll
    for (int m = 0; m < 4; ++m) {
#pragma unroll
        for (int n = 0; n < 4; ++n) {
            const int col = tn * 128 + wc + n * 16 + l15;
            float bv = 0.f;
            if (EPI == 5) bv = bias[col];
#pragma unroll
            for (int j = 0; j < 4; ++j) {
                const int rowl = wr + m * 16 + lq * 4 + j;
                const size_t idx = (size_t)(tm * 128 + rowl) * Dk + col;
                const float xv = acc[m][n][j];
                if constexpr (EPI == 0) {
                    ((__hip_bfloat16*)CoutV)[idx] = __float2bfloat16(xv * sigmoidf_fast(xv));
                } else if constexpr (EPI == 1) {
                    ((float*)CoutV)[idx] = xv;
                } else if constexpr (EPI == 4) {
                    ((__hip_bfloat16*)CoutV)[idx] = __float2bfloat16(xv);
                } else {
                    ((__hip_bfloat16*)CoutV)[idx] = __float2bfloat16(tanhf(xv + bv));
                }
            }
        }
    }
}

// Sequential scan, LDS-pipelined. 128 blocks x 1 wave; each wave owns 64 chains
// (fixed b, 64 consecutive d). Double-buffered 32-step chunks staged via
// global_load_lds (8 timesteps per width-16 call). Single wave per block =>
// no barriers; counted vmcnt at chunk end keeps cell-stores floating.
__global__ __launch_bounds__(64)
void scan_kernel(const __hip_bfloat16* __restrict__ ax,
                 const __hip_bfloat16* __restrict__ vv,
                 const float* __restrict__ h0,
                 const float* __restrict__ dal, const float* __restrict__ bal,
                 __hip_bfloat16* __restrict__ cell, float* __restrict__ hfin)
{
    constexpr int CH  = 32;        // timesteps per chunk
    constexpr int NCH = TT / CH;   // 64
    __shared__ __align__(16) __hip_bfloat16 lA[2][CH * 64];
    __shared__ __align__(16) __hip_bfloat16 lV[2][CH * 64];

    const int tid = threadIdx.x;          // 0..63
    const int bx  = blockIdx.x;           // 0..127
    const int b   = bx >> 4;
    const int d0  = (bx & 15) * 64;
    const int d   = d0 + tid;
    const int g   = b * Dk + d;

    float h = h0[g];
    const float ba  = bal[d];
    const float nda = -dal[d];

    const size_t sbase = (size_t)b * TT * Dk + d0;   // + t*Dk + (elem in [0,64))

    // per-lane pieces of the staging addresses
    const int sl = tid >> 3;          // step-in-group 0..7
    const int co = (tid & 7) * 8;     // element offset within 64-wide row

    // stage chunk `ck` into buffer `buf`: 4 groups x (ax,v) = 8 width-16 calls
    auto issue = [&](int ck, int buf) {
#pragma unroll
        for (int grp = 0; grp < 4; ++grp) {
            const size_t off = sbase + (size_t)(ck * CH + grp * 8 + sl) * Dk + co;
            gload_lds16(ax + off, (void*)&lA[buf][grp * 512]);
            gload_lds16(vv + off, (void*)&lV[buf][grp * 512]);
        }
    };

    issue(0, 0);
    asm volatile("s_waitcnt vmcnt(0)" ::: "memory");
    __builtin_amdgcn_sched_barrier(0);

    for (int k = 0; k < NCH; ++k) {
        const int buf = k & 1;
        if (k + 1 < NCH) issue(k + 1, buf ^ 1);
        __builtin_amdgcn_sched_barrier(0);

        const size_t cbase = sbase + (size_t)(k * CH) * Dk + tid;
#pragma unroll
        for (int s = 0; s < CH; ++s) {
            const float a  = __bfloat162float(lA[buf][s * 64 + tid]);
            const float V  = __bfloat162float(lV[buf][s * 64 + tid]);
            const float E  = __expf(-(a + ba));          // off the dependent chain
            const float u  = __expf(nda * h);
            const float al = FAST_RCP(fmaf(E, u, 1.f));  // sigmoid(ax+da*h+ba)
            h = fmaf(al, h - V, V);
            const float sg = FAST_RCP(1.f + __expf(-h));
            cell[cbase + (size_t)s * Dk] = __float2bfloat16(h * h * sg);
        }
        __builtin_amdgcn_sched_barrier(0);
        if (k + 1 < NCH) {
            // outstanding (FIFO): [8 loads of chunk k+1][32 stores of chunk k]
            // vmcnt(32): loads complete, stores keep floating
            asm volatile("s_waitcnt vmcnt(32)" ::: "memory");
        }
        __builtin_amdgcn_sched_barrier(0);
    }

    hfin[g] = h;
}

extern "C" void kernel_launch(void* const* d_in, const int* in_sizes, int n_in,
                              void* d_out, int out_size, void* d_ws, size_t ws_size,
                              hipStream_t stream)
{
    const float* x     = (const float*)d_in[0];
    const float* h0    = (const float*)d_in[1];
    const float* W_in  = (const float*)d_in[2];
    const float* W_al  = (const float*)d_in[3];
    const float* d_al  = (const float*)d_in[4];
    const float* b_al  = (const float*)d_in[5];
    const float* W_x   = (const float*)d_in[6];
    const float* b_v   = (const float*)d_in[7];
    const float* W_out = (const float*)d_in[8];

    float* out  = (float*)d_out;
    float* hfin = out + (size_t)MROWS * Dk;

    char* ws = (char*)d_ws;
    const size_t bfBuf = (size_t)MROWS * Dk * sizeof(__hip_bfloat16);  // 33.5 MB
    const size_t wBuf  = (size_t)Dk * Dk * sizeof(__hip_bfloat16);     // 2 MB

    __hip_bfloat16* xb    = (__hip_bfloat16*)(ws);
    __hip_bfloat16* Winb  = (__hip_bfloat16*)(ws + bfBuf);
    __hip_bfloat16* Walb  = (__hip_bfloat16*)(ws + bfBuf + wBuf);
    __hip_bfloat16* Wxb   = (__hip_bfloat16*)(ws + bfBuf + 2 * wBuf);
    __hip_bfloat16* Woutb = (__hip_bfloat16*)(ws + bfBuf + 3 * wBuf);
    char* rest = ws + bfBuf + 4 * wBuf;
    __hip_bfloat16* xproj = (__hip_bfloat16*)rest;
    __hip_bfloat16* axb   = (__hip_bfloat16*)(rest + bfBuf);
    __hip_bfloat16* vb    = (__hip_bfloat16*)(rest + 2 * bfBuf);
    __hip_bfloat16* cellb = xb;  // x dead after GEMM1

    dim3 blk(256);
    cvt_f32_bf16<<<dim3(MROWS * Dk / 1024), blk, 0, stream>>>(x, xb, MROWS * Dk);
    cvt_f32_bf16<<<dim3(Dk * Dk / 1024), blk, 0, stream>>>(W_in,  Winb,  Dk * Dk);
    cvt_f32_bf16<<<dim3(Dk * Dk / 1024), blk, 0, stream>>>(W_al,  Walb,  Dk * Dk);
    cvt_f32_bf16<<<dim3(Dk * Dk / 1024), blk, 0, stream>>>(W_x,   Wxb,   Dk * Dk);
    cvt_f32_bf16<<<dim3(Dk * Dk / 1024), blk, 0, stream>>>(W_out, Woutb, Dk * Dk);

    dim3 grid(1024);
    gemm_bt<0><<<grid, blk, 0, stream>>>(xb,    Winb,  nullptr, xproj);
    gemm_bt<4><<<grid, blk, 0, stream>>>(xproj, Walb,  nullptr, axb);
    gemm_bt<5><<<grid, blk, 0, stream>>>(xproj, Wxb,   b_v,     vb);
    scan_kernel<<<dim3(128), dim3(64), 0, stream>>>(axb, vb, h0, d_al, b_al, cellb, hfin);
    gemm_bt<1><<<grid, blk, 0, stream>>>(cellb, Woutb, nullptr, out);
}

// Round 4
// 398.930 us; speedup vs baseline: 1.6774x; 1.0339x over previous
//
#include <hip/hip_runtime.h>
#include <hip/hip_bf16.h>

typedef __attribute__((ext_vector_type(8))) short short8;
typedef __attribute__((ext_vector_type(4))) short short4v;
typedef __attribute__((ext_vector_type(4))) float f32x4;

#define Dk 1024
#define TT 2048
#define BB 8
#define MROWS (BB * TT)   // 16384

#if defined(__has_builtin)
#if __has_builtin(__builtin_amdgcn_rcpf)
#define FAST_RCP(x) __builtin_amdgcn_rcpf(x)
#endif
#if __has_builtin(__builtin_amdgcn_exp2f)
#define FAST_EXP2(x) __builtin_amdgcn_exp2f(x)
#endif
#endif
#ifndef FAST_RCP
#define FAST_RCP(x) (1.f / (x))
#endif
#ifndef FAST_EXP2
#define FAST_EXP2(x) exp2f(x)
#endif

__device__ __forceinline__ void gload_lds16(const void* g, void* l) {
    __builtin_amdgcn_global_load_lds(
        (const __attribute__((address_space(1))) void*)g,
        (__attribute__((address_space(3))) void*)l, 16, 0, 0);
}

__device__ __forceinline__ float sigmoidf_fast(float x) {
    return FAST_RCP(1.f + __expf(-x));
}

__device__ __forceinline__ unsigned short bf16_bits(float x) {
    union { __hip_bfloat16 h; unsigned short u; } c;
    c.h = __float2bfloat16(x);
    return c.u;
}

// fp32 -> bf16 conversion, 4 elems/thread, n % 1024 == 0
__global__ __launch_bounds__(256)
void cvt_f32_bf16(const float* __restrict__ in, __hip_bfloat16* __restrict__ out, int n) {
    const int i = (blockIdx.x * 256 + threadIdx.x) * 4;
    if (i >= n) return;
    const float4 v = *(const float4*)(in + i);
    __hip_bfloat16 tmp[4];
    tmp[0] = __float2bfloat16(v.x);
    tmp[1] = __float2bfloat16(v.y);
    tmp[2] = __float2bfloat16(v.z);
    tmp[3] = __float2bfloat16(v.w);
    *(short4v*)(out + i) = *(const short4v*)tmp;
}

// C = epi(A * B^T). A: [M x 1024] bf16 rm, Bw: [1024 x 1024] bf16 rm.
// EPI: 0 silu->bf16 | 1 plain->f32
template<int EPI>
__global__ __launch_bounds__(256)
void gemm_bt(const __hip_bfloat16* __restrict__ A,
             const __hip_bfloat16* __restrict__ Bw,
             void* __restrict__ CoutV)
{
    __shared__ __hip_bfloat16 sA[128 * 32];
    __shared__ __hip_bfloat16 sB[128 * 32];

    const int tid  = threadIdx.x;
    const int tn   = blockIdx.x & 7;
    const int tm   = blockIdx.x >> 3;
    const int lane = tid & 63;
    const int w    = tid >> 6;
    const int wr   = (w >> 1) * 64;
    const int wc   = (w & 1) * 64;
    const int l15  = lane & 15;
    const int lq   = lane >> 4;

    f32x4 acc[4][4];
#pragma unroll
    for (int m = 0; m < 4; ++m)
#pragma unroll
        for (int n = 0; n < 4; ++n)
            acc[m][n] = (f32x4){0.f, 0.f, 0.f, 0.f};

    const size_t baseA = (size_t)(tm * 128) * Dk;
    const size_t baseB = (size_t)(tn * 128) * Dk;

    for (int k0 = 0; k0 < Dk; k0 += 32) {
#pragma unroll
        for (int i = 0; i < 2; ++i) {
            const int li  = i * 256 + tid;
            const int row = li >> 2;
            const int cb  = li & 3;
            gload_lds16(A  + baseA + (size_t)row * Dk + k0 + cb * 8,
                        (char*)sA + li * 16);
            gload_lds16(Bw + baseB + (size_t)row * Dk + k0 + cb * 8,
                        (char*)sB + li * 16);
        }
        __syncthreads();

        short8 af[4], bfr[4];
#pragma unroll
        for (int m = 0; m < 4; ++m)
            af[m] = *(const short8*)(sA + (wr + m * 16 + l15) * 32 + lq * 8);
#pragma unroll
        for (int n = 0; n < 4; ++n)
            bfr[n] = *(const short8*)(sB + (wc + n * 16 + l15) * 32 + lq * 8);

#pragma unroll
        for (int m = 0; m < 4; ++m)
#pragma unroll
            for (int n = 0; n < 4; ++n)
                acc[m][n] = __builtin_amdgcn_mfma_f32_16x16x32_bf16(
                    af[m], bfr[n], acc[m][n], 0, 0, 0);
        __syncthreads();
    }

#pragma unroll
    for (int m = 0; m < 4; ++m) {
#pragma unroll
        for (int n = 0; n < 4; ++n) {
            const int col = tn * 128 + wc + n * 16 + l15;
#pragma unroll
            for (int j = 0; j < 4; ++j) {
                const int rowl = wr + m * 16 + lq * 4 + j;
                const size_t idx = (size_t)(tm * 128 + rowl) * Dk + col;
                const float xv = acc[m][n][j];
                if constexpr (EPI == 0) {
                    ((__hip_bfloat16*)CoutV)[idx] = __float2bfloat16(xv * sigmoidf_fast(xv));
                } else {
                    ((float*)CoutV)[idx] = xv;
                }
            }
        }
    }
}

// Fused GEMM2+3: EV[idx] = pack(E = exp(-(A*W_al^T + b_alpha)), V = tanh(A*W_x^T + b_v))
// E in low 16 bits, V in high 16 bits (both bf16).
__global__ __launch_bounds__(256)
void gemm23(const __hip_bfloat16* __restrict__ A,
            const __hip_bfloat16* __restrict__ B1,   // W_alpha
            const __hip_bfloat16* __restrict__ B2,   // W_x
            const float* __restrict__ bal,
            const float* __restrict__ bv,
            unsigned int* __restrict__ EV)
{
    __shared__ __hip_bfloat16 sA[128 * 32];
    __shared__ __hip_bfloat16 sB1[128 * 32];
    __shared__ __hip_bfloat16 sB2[128 * 32];

    const int tid  = threadIdx.x;
    const int tn   = blockIdx.x & 7;
    const int tm   = blockIdx.x >> 3;
    const int lane = tid & 63;
    const int w    = tid >> 6;
    const int wr   = (w >> 1) * 64;
    const int wc   = (w & 1) * 64;
    const int l15  = lane & 15;
    const int lq   = lane >> 4;

    f32x4 accE[4][4], accV[4][4];
#pragma unroll
    for (int m = 0; m < 4; ++m)
#pragma unroll
        for (int n = 0; n < 4; ++n) {
            accE[m][n] = (f32x4){0.f, 0.f, 0.f, 0.f};
            accV[m][n] = (f32x4){0.f, 0.f, 0.f, 0.f};
        }

    const size_t baseA = (size_t)(tm * 128) * Dk;
    const size_t baseB = (size_t)(tn * 128) * Dk;

    for (int k0 = 0; k0 < Dk; k0 += 32) {
#pragma unroll
        for (int i = 0; i < 2; ++i) {
            const int li  = i * 256 + tid;
            const int row = li >> 2;
            const int cb  = li & 3;
            const size_t go = (size_t)row * Dk + k0 + cb * 8;
            gload_lds16(A  + baseA + go, (char*)sA  + li * 16);
            gload_lds16(B1 + baseB + go, (char*)sB1 + li * 16);
            gload_lds16(B2 + baseB + go, (char*)sB2 + li * 16);
        }
        __syncthreads();

        short8 af[4], b1f[4], b2f[4];
#pragma unroll
        for (int m = 0; m < 4; ++m)
            af[m] = *(const short8*)(sA + (wr + m * 16 + l15) * 32 + lq * 8);
#pragma unroll
        for (int n = 0; n < 4; ++n) {
            b1f[n] = *(const short8*)(sB1 + (wc + n * 16 + l15) * 32 + lq * 8);
            b2f[n] = *(const short8*)(sB2 + (wc + n * 16 + l15) * 32 + lq * 8);
        }

#pragma unroll
        for (int m = 0; m < 4; ++m)
#pragma unroll
            for (int n = 0; n < 4; ++n) {
                accE[m][n] = __builtin_amdgcn_mfma_f32_16x16x32_bf16(
                    af[m], b1f[n], accE[m][n], 0, 0, 0);
                accV[m][n] = __builtin_amdgcn_mfma_f32_16x16x32_bf16(
                    af[m], b2f[n], accV[m][n], 0, 0, 0);
            }
        __syncthreads();
    }

#pragma unroll
    for (int m = 0; m < 4; ++m) {
#pragma unroll
        for (int n = 0; n < 4; ++n) {
            const int col = tn * 128 + wc + n * 16 + l15;
            const float ba = bal[col];
            const float bv_ = bv[col];
#pragma unroll
            for (int j = 0; j < 4; ++j) {
                const int rowl = wr + m * 16 + lq * 4 + j;
                const size_t idx = (size_t)(tm * 128 + rowl) * Dk + col;
                const float E = __expf(-(accE[m][n][j] + ba));
                const float V = tanhf(accV[m][n][j] + bv_);
                EV[idx] = (unsigned int)bf16_bits(E)
                        | ((unsigned int)bf16_bits(V) << 16);
            }
        }
    }
}

// Sequential scan v3. 128 blocks x 1 wave; wave owns 64 chains (fixed b,
// 64 consecutive d). Double-buffered 32-step chunks of packed (E,V) staged via
// global_load_lds. Per step: 1 ds_read_b32 + bit-unpack + {exp2, fma, rcp, fma}.
// Stores h (bf16); cell = h^2*sigmoid(h) computed by gpass afterwards.
__global__ __launch_bounds__(64)
void scan_kernel(const unsigned int* __restrict__ EV,
                 const float* __restrict__ h0,
                 const float* __restrict__ dal,
                 __hip_bfloat16* __restrict__ hout, float* __restrict__ hfin)
{
    constexpr int CH  = 32;        // timesteps per chunk
    constexpr int NCH = TT / CH;   // 64
    __shared__ __align__(16) unsigned int lEV[2][CH * 64];

    const int tid = threadIdx.x;          // 0..63
    const int bx  = blockIdx.x;           // 0..127
    const int b   = bx >> 4;
    const int d0  = (bx & 15) * 64;
    const int d   = d0 + tid;
    const int g   = b * Dk + d;

    float h = h0[g];
    const float nl2 = -dal[d] * 1.44269504089f;   // -d_alpha * log2(e)

    const size_t sbase = (size_t)b * TT * Dk + d0;   // dword index base

    // staging: per call 64 lanes x 16B = 4 step-rows of 64 dwords
    const int sl = tid >> 4;          // step within group 0..3
    const int co = (tid & 15) * 4;    // dword offset within 64-wide row

    auto issue = [&](int ck, int buf) {
#pragma unroll
        for (int grp = 0; grp < 8; ++grp) {
            const size_t off = sbase + (size_t)(ck * CH + grp * 4 + sl) * Dk + co;
            gload_lds16(EV + off, (void*)&lEV[buf][grp * 256]);
        }
    };

    issue(0, 0);
    asm volatile("s_waitcnt vmcnt(0)" ::: "memory");
    __builtin_amdgcn_sched_barrier(0);

    for (int k = 0; k < NCH; ++k) {
        const int buf = k & 1;
        if (k + 1 < NCH) issue(k + 1, buf ^ 1);
        __builtin_amdgcn_sched_barrier(0);

        const size_t cbase = sbase + (size_t)(k * CH) * Dk + tid;
#pragma unroll
        for (int s = 0; s < CH; ++s) {
            const unsigned int wv = lEV[buf][s * 64 + tid];
            const float E = __uint_as_float(wv << 16);
            const float V = __uint_as_float(wv & 0xffff0000u);
            const float u  = FAST_EXP2(nl2 * h);
            const float al = FAST_RCP(fmaf(E, u, 1.f));   // sigmoid(ax+da*h+ba)
            h = fmaf(al, h - V, V);
            hout[cbase + (size_t)s * Dk] = __float2bfloat16(h);
        }
        __builtin_amdgcn_sched_barrier(0);
        if (k + 1 < NCH) {
            // FIFO: [8 loads of chunk k+1][32 stores of chunk k]; vmcnt(32)
            // retires the loads, lets stores float.
            asm volatile("s_waitcnt vmcnt(32)" ::: "memory");
        }
        __builtin_amdgcn_sched_barrier(0);
    }

    hfin[g] = h;
}

// cell = h^2 * sigmoid(h), bf16 -> bf16, 8 elems/thread, grid-stride
__global__ __launch_bounds__(256)
void gpass(const __hip_bfloat16* __restrict__ hin,
           __hip_bfloat16* __restrict__ cell, int n)
{
    const int stride = gridDim.x * 256 * 8;
    for (int i = (blockIdx.x * 256 + threadIdx.x) * 8; i < n; i += stride) {
        const short8 v = *(const short8*)(hin + i);
        short8 r;
#pragma unroll
        for (int j = 0; j < 8; ++j) {
            const float x = __uint_as_float(((unsigned int)(unsigned short)v[j]) << 16);
            const float s = FAST_RCP(1.f + __expf(-x));
            r[j] = (short)bf16_bits(x * x * s);
        }
        *(short8*)(cell + i) = r;
    }
}

extern "C" void kernel_launch(void* const* d_in, const int* in_sizes, int n_in,
                              void* d_out, int out_size, void* d_ws, size_t ws_size,
                              hipStream_t stream)
{
    const float* x     = (const float*)d_in[0];
    const float* h0    = (const float*)d_in[1];
    const float* W_in  = (const float*)d_in[2];
    const float* W_al  = (const float*)d_in[3];
    const float* d_al  = (const float*)d_in[4];
    const float* b_al  = (const float*)d_in[5];
    const float* W_x   = (const float*)d_in[6];
    const float* b_v   = (const float*)d_in[7];
    const float* W_out = (const float*)d_in[8];

    float* out  = (float*)d_out;
    float* hfin = out + (size_t)MROWS * Dk;

    char* ws = (char*)d_ws;
    const size_t bfBuf = (size_t)MROWS * Dk * sizeof(__hip_bfloat16);  // 33.5 MB
    const size_t wBuf  = (size_t)Dk * Dk * sizeof(__hip_bfloat16);     // 2 MB

    __hip_bfloat16* xb    = (__hip_bfloat16*)(ws);                 // x bf16, then h
    __hip_bfloat16* Winb  = (__hip_bfloat16*)(ws + bfBuf);
    __hip_bfloat16* Walb  = (__hip_bfloat16*)(ws + bfBuf + wBuf);
    __hip_bfloat16* Wxb   = (__hip_bfloat16*)(ws + bfBuf + 2 * wBuf);
    __hip_bfloat16* Woutb = (__hip_bfloat16*)(ws + bfBuf + 3 * wBuf);
    char* rest = ws + bfBuf + 4 * wBuf;
    __hip_bfloat16* xproj = (__hip_bfloat16*)rest;                 // then cell
    unsigned int*   EVb   = (unsigned int*)(rest + bfBuf);         // 67 MB

    __hip_bfloat16* hbuf  = xb;      // x dead after GEMM1
    __hip_bfloat16* cellb = xproj;   // xproj dead after gemm23

    dim3 blk(256);
    cvt_f32_bf16<<<dim3(MROWS * Dk / 1024), blk, 0, stream>>>(x, xb, MROWS * Dk);
    cvt_f32_bf16<<<dim3(Dk * Dk / 1024), blk, 0, stream>>>(W_in,  Winb,  Dk * Dk);
    cvt_f32_bf16<<<dim3(Dk * Dk / 1024), blk, 0, stream>>>(W_al,  Walb,  Dk * Dk);
    cvt_f32_bf16<<<dim3(Dk * Dk / 1024), blk, 0, stream>>>(W_x,   Wxb,   Dk * Dk);
    cvt_f32_bf16<<<dim3(Dk * Dk / 1024), blk, 0, stream>>>(W_out, Woutb, Dk * Dk);

    dim3 grid(1024);
    gemm_bt<0><<<grid, blk, 0, stream>>>(xb, Winb, xproj);
    gemm23<<<grid, blk, 0, stream>>>(xproj, Walb, Wxb, b_al, b_v, EVb);
    scan_kernel<<<dim3(128), dim3(64), 0, stream>>>(EVb, h0, d_al, hbuf, hfin);
    gpass<<<dim3(2048), blk, 0, stream>>>(hbuf, cellb, MROWS * Dk);
    gemm_bt<1><<<grid, blk, 0, stream>>>(cellb, Woutb, out);
}

// Round 6
// 312.362 us; speedup vs baseline: 2.1423x; 1.2771x over previous
//
#include <hip/hip_runtime.h>
#include <hip/hip_bf16.h>

typedef __attribute__((ext_vector_type(8))) short short8;
typedef __attribute__((ext_vector_type(4))) short short4v;
typedef __attribute__((ext_vector_type(4))) float f32x4;

#define Dk 1024
#define TT 2048
#define BB 8
#define MROWS (BB * TT)   // 16384
#define LOG2E 1.44269504088896f

#if defined(__has_builtin)
#if __has_builtin(__builtin_amdgcn_rcpf)
#define FAST_RCP(x) __builtin_amdgcn_rcpf(x)
#endif
#if __has_builtin(__builtin_amdgcn_exp2f)
#define FAST_EXP2(x) __builtin_amdgcn_exp2f(x)
#endif
#endif
#ifndef FAST_RCP
#define FAST_RCP(x) (1.f / (x))
#endif
#ifndef FAST_EXP2
#define FAST_EXP2(x) exp2f(x)
#endif

__device__ __forceinline__ void gload_lds16(const void* g, void* l) {
    __builtin_amdgcn_global_load_lds(
        (const __attribute__((address_space(1))) void*)g,
        (__attribute__((address_space(3))) void*)l, 16, 0, 0);
}

__device__ __forceinline__ float sigmoidf_fast(float x) {
    return FAST_RCP(1.f + FAST_EXP2(-x * LOG2E));
}

__device__ __forceinline__ unsigned short bf16_bits(float x) {
    union { __hip_bfloat16 h; unsigned short u; } c;
    c.h = __float2bfloat16(x);
    return c.u;
}

// fp32 -> bf16, 4 elems/thread
__global__ __launch_bounds__(256)
void cvt_f32_bf16(const float* __restrict__ in, __hip_bfloat16* __restrict__ out, int n) {
    const int i = (blockIdx.x * 256 + threadIdx.x) * 4;
    if (i >= n) return;
    const float4 v = *(const float4*)(in + i);
    __hip_bfloat16 tmp[4];
    tmp[0] = __float2bfloat16(v.x);
    tmp[1] = __float2bfloat16(v.y);
    tmp[2] = __float2bfloat16(v.z);
    tmp[3] = __float2bfloat16(v.w);
    *(short4v*)(out + i) = *(const short4v*)tmp;
}

// all four 1024x1024 weights in one launch: 1024 blocks per weight
__global__ __launch_bounds__(256)
void cvt_w4(const float* __restrict__ w0, const float* __restrict__ w1,
            const float* __restrict__ w2, const float* __restrict__ w3,
            __hip_bfloat16* __restrict__ o0, __hip_bfloat16* __restrict__ o1,
            __hip_bfloat16* __restrict__ o2, __hip_bfloat16* __restrict__ o3)
{
    const int which = blockIdx.x >> 10;
    const int i = ((blockIdx.x & 1023) * 256 + threadIdx.x) * 4;
    const float* in = which == 0 ? w0 : which == 1 ? w1 : which == 2 ? w2 : w3;
    __hip_bfloat16* out = which == 0 ? o0 : which == 1 ? o1 : which == 2 ? o2 : o3;
    const float4 v = *(const float4*)(in + i);
    __hip_bfloat16 tmp[4];
    tmp[0] = __float2bfloat16(v.x);
    tmp[1] = __float2bfloat16(v.y);
    tmp[2] = __float2bfloat16(v.z);
    tmp[3] = __float2bfloat16(v.w);
    *(short4v*)(out + i) = *(const short4v*)tmp;
}

// C = epi(A * B^T). A: [M x 1024] bf16 rm, Bw: [1024 x 1024] bf16 rm.
// EPI: 0 silu->bf16 | 1 plain->f32
//      6 E=exp(-(x+bias)) -> u16 halfword @ 2*idx   (packed EV low)
//      7 V=tanh(x+bias)   -> u16 halfword @ 2*idx+1 (packed EV high)
template<int EPI>
__global__ __launch_bounds__(256)
void gemm_bt(const __hip_bfloat16* __restrict__ A,
             const __hip_bfloat16* __restrict__ Bw,
             const float* __restrict__ bias,
             void* __restrict__ CoutV)
{
    __shared__ __hip_bfloat16 sA[128 * 32];
    __shared__ __hip_bfloat16 sB[128 * 32];

    const int tid  = threadIdx.x;
    // XCD-aware swizzle: blocks with the same A-panel (same tm) land on one XCD
    const int bid  = blockIdx.x;
    const int nbid = (bid & 7) * 128 + (bid >> 3);
    const int tn   = nbid & 7;
    const int tm   = nbid >> 3;
    const int lane = tid & 63;
    const int w    = tid >> 6;
    const int wr   = (w >> 1) * 64;
    const int wc   = (w & 1) * 64;
    const int l15  = lane & 15;
    const int lq   = lane >> 4;

    f32x4 acc[4][4];
#pragma unroll
    for (int m = 0; m < 4; ++m)
#pragma unroll
        for (int n = 0; n < 4; ++n)
            acc[m][n] = (f32x4){0.f, 0.f, 0.f, 0.f};

    const size_t baseA = (size_t)(tm * 128) * Dk;
    const size_t baseB = (size_t)(tn * 128) * Dk;

    for (int k0 = 0; k0 < Dk; k0 += 32) {
#pragma unroll
        for (int i = 0; i < 2; ++i) {
            const int li  = i * 256 + tid;
            const int row = li >> 2;
            const int cb  = li & 3;
            gload_lds16(A  + baseA + (size_t)row * Dk + k0 + cb * 8,
                        (char*)sA + li * 16);
            gload_lds16(Bw + baseB + (size_t)row * Dk + k0 + cb * 8,
                        (char*)sB + li * 16);
        }
        __syncthreads();

        short8 af[4], bfr[4];
#pragma unroll
        for (int m = 0; m < 4; ++m)
            af[m] = *(const short8*)(sA + (wr + m * 16 + l15) * 32 + lq * 8);
#pragma unroll
        for (int n = 0; n < 4; ++n)
            bfr[n] = *(const short8*)(sB + (wc + n * 16 + l15) * 32 + lq * 8);

#pragma unroll
        for (int m = 0; m < 4; ++m)
#pragma unroll
            for (int n = 0; n < 4; ++n)
                acc[m][n] = __builtin_amdgcn_mfma_f32_16x16x32_bf16(
                    af[m], bfr[n], acc[m][n], 0, 0, 0);
        __syncthreads();
    }

#pragma unroll
    for (int m = 0; m < 4; ++m) {
#pragma unroll
        for (int n = 0; n < 4; ++n) {
            const int col = tn * 128 + wc + n * 16 + l15;
            float bv_ = 0.f;
            if (EPI == 6 || EPI == 7) bv_ = bias[col];
#pragma unroll
            for (int j = 0; j < 4; ++j) {
                const int rowl = wr + m * 16 + lq * 4 + j;
                const size_t idx = (size_t)(tm * 128 + rowl) * Dk + col;
                const float xv = acc[m][n][j];
                if constexpr (EPI == 0) {
                    ((__hip_bfloat16*)CoutV)[idx] =
                        __float2bfloat16(xv * sigmoidf_fast(xv));
                } else if constexpr (EPI == 1) {
                    ((float*)CoutV)[idx] = xv;
                } else if constexpr (EPI == 6) {
                    const float e = FAST_EXP2(-(xv + bv_) * LOG2E);
                    ((unsigned short*)CoutV)[idx * 2] = bf16_bits(e);
                } else {   // EPI == 7: tanh via exp2, sign-safe
                    const float y  = xv + bv_;
                    const float e  = FAST_EXP2(fabsf(y) * (2.f * LOG2E));
                    float t = 1.f - 2.f * FAST_RCP(e + 1.f);
                    t = copysignf(t, y);
                    ((unsigned short*)CoutV)[idx * 2 + 1] = bf16_bits(t);
                }
            }
        }
    }
}

// Sequential scan. 128 blocks x 1 wave; wave owns 64 chains (fixed b, 64
// consecutive d). Double-buffered 32-step chunks of packed (E,V) staged via
// global_load_lds. Per step: 1 ds_read_b32 + bit-unpack + {exp2, fma, rcp, fma}.
// Stores h (bf16); cell computed by gpass.
__global__ __launch_bounds__(64)
void scan_kernel(const unsigned int* __restrict__ EV,
                 const float* __restrict__ h0,
                 const float* __restrict__ dal,
                 __hip_bfloat16* __restrict__ hout, float* __restrict__ hfin)
{
    constexpr int CH  = 32;
    constexpr int NCH = TT / CH;   // 64
    __shared__ __align__(16) unsigned int lEV[2][CH * 64];

    const int tid = threadIdx.x;          // 0..63
    const int bx  = blockIdx.x;           // 0..127
    const int b   = bx >> 4;
    const int d0  = (bx & 15) * 64;
    const int d   = d0 + tid;
    const int g   = b * Dk + d;

    float h = h0[g];
    const float nl2 = -dal[d] * LOG2E;

    const size_t sbase = (size_t)b * TT * Dk + d0;

    const int sl = tid >> 4;
    const int co = (tid & 15) * 4;

    auto issue = [&](int ck, int buf) {
#pragma unroll
        for (int grp = 0; grp < 8; ++grp) {
            const size_t off = sbase + (size_t)(ck * CH + grp * 4 + sl) * Dk + co;
            gload_lds16(EV + off, (void*)&lEV[buf][grp * 256]);
        }
    };

    issue(0, 0);
    asm volatile("s_waitcnt vmcnt(0)" ::: "memory");
    __builtin_amdgcn_sched_barrier(0);

    for (int k = 0; k < NCH; ++k) {
        const int buf = k & 1;
        if (k + 1 < NCH) issue(k + 1, buf ^ 1);
        __builtin_amdgcn_sched_barrier(0);

        const size_t cbase = sbase + (size_t)(k * CH) * Dk + tid;
#pragma unroll
        for (int s = 0; s < CH; ++s) {
            const unsigned int wv = lEV[buf][s * 64 + tid];
            const float E = __uint_as_float(wv << 16);
            const float V = __uint_as_float(wv & 0xffff0000u);
            const float u  = FAST_EXP2(nl2 * h);
            const float al = FAST_RCP(fmaf(E, u, 1.f));
            h = fmaf(al, h - V, V);
            hout[cbase + (size_t)s * Dk] = __float2bfloat16(h);
        }
        __builtin_amdgcn_sched_barrier(0);
        if (k + 1 < NCH) {
            asm volatile("s_waitcnt vmcnt(32)" ::: "memory");
        }
        __builtin_amdgcn_sched_barrier(0);
    }

    hfin[g] = h;
}

// cell = h^2 * sigmoid(h), bf16 -> bf16, 8 elems/thread, grid-stride
__global__ __launch_bounds__(256)
void gpass(const __hip_bfloat16* __restrict__ hin,
           __hip_bfloat16* __restrict__ cell, int n)
{
    const int stride = gridDim.x * 256 * 8;
    for (int i = (blockIdx.x * 256 + threadIdx.x) * 8; i < n; i += stride) {
        const short8 v = *(const short8*)(hin + i);
        short8 r;
#pragma unroll
        for (int j = 0; j < 8; ++j) {
            const float x = __uint_as_float(((unsigned int)(unsigned short)v[j]) << 16);
            const float s = sigmoidf_fast(x);
            r[j] = (short)bf16_bits(x * x * s);
        }
        *(short8*)(cell + i) = r;
    }
}

extern "C" void kernel_launch(void* const* d_in, const int* in_sizes, int n_in,
                              void* d_out, int out_size, void* d_ws, size_t ws_size,
                              hipStream_t stream)
{
    const float* x     = (const float*)d_in[0];
    const float* h0    = (const float*)d_in[1];
    const float* W_in  = (const float*)d_in[2];
    const float* W_al  = (const float*)d_in[3];
    const float* d_al  = (const float*)d_in[4];
    const float* b_al  = (const float*)d_in[5];
    const float* W_x   = (const float*)d_in[6];
    const float* b_v   = (const float*)d_in[7];
    const float* W_out = (const float*)d_in[8];

    float* out  = (float*)d_out;
    float* hfin = out + (size_t)MROWS * Dk;

    char* ws = (char*)d_ws;
    const size_t bfBuf = (size_t)MROWS * Dk * sizeof(__hip_bfloat16);  // 33.5 MB
    const size_t wBuf  = (size_t)Dk * Dk * sizeof(__hip_bfloat16);     // 2 MB

    __hip_bfloat16* xb    = (__hip_bfloat16*)(ws);                 // x bf16, then h
    __hip_bfloat16* Winb  = (__hip_bfloat16*)(ws + bfBuf);
    __hip_bfloat16* Walb  = (__hip_bfloat16*)(ws + bfBuf + wBuf);
    __hip_bfloat16* Wxb   = (__hip_bfloat16*)(ws + bfBuf + 2 * wBuf);
    __hip_bfloat16* Woutb = (__hip_bfloat16*)(ws + bfBuf + 3 * wBuf);
    char* rest = ws + bfBuf + 4 * wBuf;
    __hip_bfloat16* xproj = (__hip_bfloat16*)rest;                 // then cell
    unsigned int*   EVb   = (unsigned int*)(rest + bfBuf);         // 67 MB

    __hip_bfloat16* hbuf  = xb;      // x dead after GEMM1
    __hip_bfloat16* cellb = xproj;   // xproj dead after E/V GEMMs

    dim3 blk(256);
    cvt_f32_bf16<<<dim3(MROWS * Dk / 1024), blk, 0, stream>>>(x, xb, MROWS * Dk);
    cvt_w4<<<dim3(4096), blk, 0, stream>>>(W_in, W_al, W_x, W_out,
                                           Winb, Walb, Wxb, Woutb);

    dim3 grid(1024);
    gemm_bt<0><<<grid, blk, 0, stream>>>(xb,    Winb,  nullptr, xproj);
    gemm_bt<6><<<grid, blk, 0, stream>>>(xproj, Walb,  b_al,    EVb);
    gemm_bt<7><<<grid, blk, 0, stream>>>(xproj, Wxb,   b_v,     EVb);
    scan_kernel<<<dim3(128), dim3(64), 0, stream>>>(EVb, h0, d_al, hbuf, hfin);
    gpass<<<dim3(2048), blk, 0, stream>>>(hbuf, cellb, MROWS * Dk);
    gemm_bt<1><<<grid, blk, 0, stream>>>(cellb, Woutb, nullptr, out);
}

// Round 7
// 277.831 us; speedup vs baseline: 2.4085x; 1.1243x over previous
//
#include <hip/hip_runtime.h>
#include <hip/hip_bf16.h>

typedef __attribute__((ext_vector_type(8))) short short8;
typedef __attribute__((ext_vector_type(4))) short short4v;
typedef __attribute__((ext_vector_type(4))) float f32x4;

#define Dk 1024
#define TT 2048
#define BB 8
#define MROWS (BB * TT)   // 16384
#define LOG2E 1.44269504088896f

#if defined(__has_builtin)
#if __has_builtin(__builtin_amdgcn_rcpf)
#define FAST_RCP(x) __builtin_amdgcn_rcpf(x)
#endif
#if __has_builtin(__builtin_amdgcn_exp2f)
#define FAST_EXP2(x) __builtin_amdgcn_exp2f(x)
#endif
#endif
#ifndef FAST_RCP
#define FAST_RCP(x) (1.f / (x))
#endif
#ifndef FAST_EXP2
#define FAST_EXP2(x) exp2f(x)
#endif

__device__ __forceinline__ void gload_lds16(const void* g, void* l) {
    __builtin_amdgcn_global_load_lds(
        (const __attribute__((address_space(1))) void*)g,
        (__attribute__((address_space(3))) void*)l, 16, 0, 0);
}

__device__ __forceinline__ float sigmoidf_fast(float x) {
    return FAST_RCP(1.f + FAST_EXP2(-x * LOG2E));
}

__device__ __forceinline__ unsigned short bf16_bits(float x) {
    union { __hip_bfloat16 h; unsigned short u; } c;
    c.h = __float2bfloat16(x);
    return c.u;
}

// fp32 -> bf16, 4 elems/thread
__global__ __launch_bounds__(256)
void cvt_f32_bf16(const float* __restrict__ in, __hip_bfloat16* __restrict__ out, int n) {
    const int i = (blockIdx.x * 256 + threadIdx.x) * 4;
    if (i >= n) return;
    const float4 v = *(const float4*)(in + i);
    __hip_bfloat16 tmp[4];
    tmp[0] = __float2bfloat16(v.x);
    tmp[1] = __float2bfloat16(v.y);
    tmp[2] = __float2bfloat16(v.z);
    tmp[3] = __float2bfloat16(v.w);
    *(short4v*)(out + i) = *(const short4v*)tmp;
}

// all four 1024x1024 weights in one launch
__global__ __launch_bounds__(256)
void cvt_w4(const float* __restrict__ w0, const float* __restrict__ w1,
            const float* __restrict__ w2, const float* __restrict__ w3,
            __hip_bfloat16* __restrict__ o0, __hip_bfloat16* __restrict__ o1,
            __hip_bfloat16* __restrict__ o2, __hip_bfloat16* __restrict__ o3)
{
    const int which = blockIdx.x >> 10;
    const int i = ((blockIdx.x & 1023) * 256 + threadIdx.x) * 4;
    const float* in = which == 0 ? w0 : which == 1 ? w1 : which == 2 ? w2 : w3;
    __hip_bfloat16* out = which == 0 ? o0 : which == 1 ? o1 : which == 2 ? o2 : o3;
    const float4 v = *(const float4*)(in + i);
    __hip_bfloat16 tmp[4];
    tmp[0] = __float2bfloat16(v.x);
    tmp[1] = __float2bfloat16(v.y);
    tmp[2] = __float2bfloat16(v.z);
    tmp[3] = __float2bfloat16(v.w);
    *(short4v*)(out + i) = *(const short4v*)tmp;
}

// C = epi(A * B^T). A: [M x 1024] bf16 rm, Bw: [1024 x 1024] bf16 rm.
// Double-buffered LDS, stage-ahead, ONE barrier per K-iter (T3-min recipe).
// EPI: 0 silu->bf16 | 1 plain->f32
template<int EPI>
__global__ __launch_bounds__(256)
void gemm_bt(const __hip_bfloat16* __restrict__ A,
             const __hip_bfloat16* __restrict__ Bw,
             void* __restrict__ CoutV)
{
    __shared__ __hip_bfloat16 sA[2][128 * 32];
    __shared__ __hip_bfloat16 sB[2][128 * 32];

    const int tid  = threadIdx.x;
    const int bid  = blockIdx.x;
    const int nbid = (bid & 7) * 128 + (bid >> 3);   // XCD swizzle (1024 % 8 == 0)
    const int tn   = nbid & 7;
    const int tm   = nbid >> 3;
    const int lane = tid & 63;
    const int w    = tid >> 6;
    const int wr   = (w >> 1) * 64;
    const int wc   = (w & 1) * 64;
    const int l15  = lane & 15;
    const int lq   = lane >> 4;

    f32x4 acc[4][4];
#pragma unroll
    for (int m = 0; m < 4; ++m)
#pragma unroll
        for (int n = 0; n < 4; ++n)
            acc[m][n] = (f32x4){0.f, 0.f, 0.f, 0.f};

    const size_t baseA = (size_t)(tm * 128) * Dk;
    const size_t baseB = (size_t)(tn * 128) * Dk;

    auto stage = [&](int k0, int buf) {
#pragma unroll
        for (int i = 0; i < 2; ++i) {
            const int li  = i * 256 + tid;
            const int row = li >> 2;
            const int cb  = li & 3;
            const size_t go = (size_t)row * Dk + k0 + cb * 8;
            gload_lds16(A  + baseA + go, (char*)sA[buf] + li * 16);
            gload_lds16(Bw + baseB + go, (char*)sB[buf] + li * 16);
        }
    };

    stage(0, 0);
    __syncthreads();   // drains vmcnt(0): buf0 ready

    int buf = 0;
    for (int k0 = 0; k0 < Dk; k0 += 32) {
        if (k0 + 32 < Dk) stage(k0 + 32, buf ^ 1);   // issue BEFORE compute

        short8 af[4], bfr[4];
#pragma unroll
        for (int m = 0; m < 4; ++m)
            af[m] = *(const short8*)(sA[buf] + (wr + m * 16 + l15) * 32 + lq * 8);
#pragma unroll
        for (int n = 0; n < 4; ++n)
            bfr[n] = *(const short8*)(sB[buf] + (wc + n * 16 + l15) * 32 + lq * 8);

#pragma unroll
        for (int m = 0; m < 4; ++m)
#pragma unroll
            for (int n = 0; n < 4; ++n)
                acc[m][n] = __builtin_amdgcn_mfma_f32_16x16x32_bf16(
                    af[m], bfr[n], acc[m][n], 0, 0, 0);

        __syncthreads();   // one drain+barrier per iter, AFTER compute
        buf ^= 1;
    }

#pragma unroll
    for (int m = 0; m < 4; ++m) {
#pragma unroll
        for (int n = 0; n < 4; ++n) {
            const int col = tn * 128 + wc + n * 16 + l15;
#pragma unroll
            for (int j = 0; j < 4; ++j) {
                const int rowl = wr + m * 16 + lq * 4 + j;
                const size_t idx = (size_t)(tm * 128 + rowl) * Dk + col;
                const float xv = acc[m][n][j];
                if constexpr (EPI == 0) {
                    ((__hip_bfloat16*)CoutV)[idx] =
                        __float2bfloat16(xv * sigmoidf_fast(xv));
                } else {
                    ((float*)CoutV)[idx] = xv;
                }
            }
        }
    }
}

// Fused E/V GEMM, 8 waves / 512 threads. Waves 0-3 compute E-tile (W_alpha),
// waves 4-7 compute V-tile (W_x) — A-tile staged once, shared. Same 2ph-dbuf
// stage-ahead structure. Packed EV output: E -> u16 @2*idx, V -> u16 @2*idx+1.
__global__ __launch_bounds__(512)
void gemm_ev(const __hip_bfloat16* __restrict__ A,
             const __hip_bfloat16* __restrict__ B1,   // W_alpha
             const __hip_bfloat16* __restrict__ B2,   // W_x
             const float* __restrict__ bal,
             const float* __restrict__ bv,
             unsigned short* __restrict__ EV)
{
    __shared__ __hip_bfloat16 sA [2][128 * 32];
    __shared__ __hip_bfloat16 sB1[2][128 * 32];
    __shared__ __hip_bfloat16 sB2[2][128 * 32];

    const int tid  = threadIdx.x;
    const int bid  = blockIdx.x;
    const int nbid = (bid & 7) * 128 + (bid >> 3);
    const int tn   = nbid & 7;
    const int tm   = nbid >> 3;
    const int lane = tid & 63;
    const int w    = tid >> 6;       // 0..7
    const int we   = w & 3;          // position within its gemm
    const bool isV = w >= 4;
    const int wr   = (we >> 1) * 64;
    const int wc   = (we & 1) * 64;
    const int l15  = lane & 15;
    const int lq   = lane >> 4;

    f32x4 acc[4][4];
#pragma unroll
    for (int m = 0; m < 4; ++m)
#pragma unroll
        for (int n = 0; n < 4; ++n)
            acc[m][n] = (f32x4){0.f, 0.f, 0.f, 0.f};

    const size_t baseA = (size_t)(tm * 128) * Dk;
    const size_t baseB = (size_t)(tn * 128) * Dk;

    // 512 threads stage one 128x32 tile with one 16B call each
    auto stage = [&](int k0, int buf) {
        const int row = tid >> 2;
        const int cb  = tid & 3;
        const size_t go = (size_t)row * Dk + k0 + cb * 8;
        gload_lds16(A  + baseA + go, (char*)sA [buf] + tid * 16);
        gload_lds16(B1 + baseB + go, (char*)sB1[buf] + tid * 16);
        gload_lds16(B2 + baseB + go, (char*)sB2[buf] + tid * 16);
    };

    stage(0, 0);
    __syncthreads();

    int buf = 0;
    for (int k0 = 0; k0 < Dk; k0 += 32) {
        if (k0 + 32 < Dk) stage(k0 + 32, buf ^ 1);

        const __hip_bfloat16* sBx = isV ? sB2[buf] : sB1[buf];
        short8 af[4], bfr[4];
#pragma unroll
        for (int m = 0; m < 4; ++m)
            af[m] = *(const short8*)(sA[buf] + (wr + m * 16 + l15) * 32 + lq * 8);
#pragma unroll
        for (int n = 0; n < 4; ++n)
            bfr[n] = *(const short8*)(sBx + (wc + n * 16 + l15) * 32 + lq * 8);

#pragma unroll
        for (int m = 0; m < 4; ++m)
#pragma unroll
            for (int n = 0; n < 4; ++n)
                acc[m][n] = __builtin_amdgcn_mfma_f32_16x16x32_bf16(
                    af[m], bfr[n], acc[m][n], 0, 0, 0);

        __syncthreads();
        buf ^= 1;
    }

#pragma unroll
    for (int m = 0; m < 4; ++m) {
#pragma unroll
        for (int n = 0; n < 4; ++n) {
            const int col = tn * 128 + wc + n * 16 + l15;
            const float bias = isV ? bv[col] : bal[col];
#pragma unroll
            for (int j = 0; j < 4; ++j) {
                const int rowl = wr + m * 16 + lq * 4 + j;
                const size_t idx = (size_t)(tm * 128 + rowl) * Dk + col;
                const float xv = acc[m][n][j];
                if (!isV) {
                    const float e = FAST_EXP2(-(xv + bias) * LOG2E);
                    EV[idx * 2] = bf16_bits(e);
                } else {
                    const float y = xv + bias;
                    const float e = FAST_EXP2(fabsf(y) * (2.f * LOG2E));
                    float t = 1.f - 2.f * FAST_RCP(e + 1.f);
                    t = copysignf(t, y);
                    EV[idx * 2 + 1] = bf16_bits(t);
                }
            }
        }
    }
}

// Sequential scan (unchanged from round 4/6 — proven). 128 blocks x 1 wave.
__global__ __launch_bounds__(64)
void scan_kernel(const unsigned int* __restrict__ EV,
                 const float* __restrict__ h0,
                 const float* __restrict__ dal,
                 __hip_bfloat16* __restrict__ hout, float* __restrict__ hfin)
{
    constexpr int CH  = 32;
    constexpr int NCH = TT / CH;   // 64
    __shared__ __align__(16) unsigned int lEV[2][CH * 64];

    const int tid = threadIdx.x;
    const int bx  = blockIdx.x;
    const int b   = bx >> 4;
    const int d0  = (bx & 15) * 64;
    const int d   = d0 + tid;
    const int g   = b * Dk + d;

    float h = h0[g];
    const float nl2 = -dal[d] * LOG2E;

    const size_t sbase = (size_t)b * TT * Dk + d0;

    const int sl = tid >> 4;
    const int co = (tid & 15) * 4;

    auto issue = [&](int ck, int buf) {
#pragma unroll
        for (int grp = 0; grp < 8; ++grp) {
            const size_t off = sbase + (size_t)(ck * CH + grp * 4 + sl) * Dk + co;
            gload_lds16(EV + off, (void*)&lEV[buf][grp * 256]);
        }
    };

    issue(0, 0);
    asm volatile("s_waitcnt vmcnt(0)" ::: "memory");
    __builtin_amdgcn_sched_barrier(0);

    for (int k = 0; k < NCH; ++k) {
        const int buf = k & 1;
        if (k + 1 < NCH) issue(k + 1, buf ^ 1);
        __builtin_amdgcn_sched_barrier(0);

        const size_t cbase = sbase + (size_t)(k * CH) * Dk + tid;
#pragma unroll
        for (int s = 0; s < CH; ++s) {
            const unsigned int wv = lEV[buf][s * 64 + tid];
            const float E = __uint_as_float(wv << 16);
            const float V = __uint_as_float(wv & 0xffff0000u);
            const float u  = FAST_EXP2(nl2 * h);
            const float al = FAST_RCP(fmaf(E, u, 1.f));
            h = fmaf(al, h - V, V);
            hout[cbase + (size_t)s * Dk] = __float2bfloat16(h);
        }
        __builtin_amdgcn_sched_barrier(0);
        if (k + 1 < NCH) {
            asm volatile("s_waitcnt vmcnt(32)" ::: "memory");
        }
        __builtin_amdgcn_sched_barrier(0);
    }

    hfin[g] = h;
}

// cell = h^2 * sigmoid(h)
__global__ __launch_bounds__(256)
void gpass(const __hip_bfloat16* __restrict__ hin,
           __hip_bfloat16* __restrict__ cell, int n)
{
    const int stride = gridDim.x * 256 * 8;
    for (int i = (blockIdx.x * 256 + threadIdx.x) * 8; i < n; i += stride) {
        const short8 v = *(const short8*)(hin + i);
        short8 r;
#pragma unroll
        for (int j = 0; j < 8; ++j) {
            const float x = __uint_as_float(((unsigned int)(unsigned short)v[j]) << 16);
            const float s = sigmoidf_fast(x);
            r[j] = (short)bf16_bits(x * x * s);
        }
        *(short8*)(cell + i) = r;
    }
}

extern "C" void kernel_launch(void* const* d_in, const int* in_sizes, int n_in,
                              void* d_out, int out_size, void* d_ws, size_t ws_size,
                              hipStream_t stream)
{
    const float* x     = (const float*)d_in[0];
    const float* h0    = (const float*)d_in[1];
    const float* W_in  = (const float*)d_in[2];
    const float* W_al  = (const float*)d_in[3];
    const float* d_al  = (const float*)d_in[4];
    const float* b_al  = (const float*)d_in[5];
    const float* W_x   = (const float*)d_in[6];
    const float* b_v   = (const float*)d_in[7];
    const float* W_out = (const float*)d_in[8];

    float* out  = (float*)d_out;
    float* hfin = out + (size_t)MROWS * Dk;

    char* ws = (char*)d_ws;
    const size_t bfBuf = (size_t)MROWS * Dk * sizeof(__hip_bfloat16);  // 33.5 MB
    const size_t wBuf  = (size_t)Dk * Dk * sizeof(__hip_bfloat16);     // 2 MB

    __hip_bfloat16* xb    = (__hip_bfloat16*)(ws);                 // x bf16, then h
    __hip_bfloat16* Winb  = (__hip_bfloat16*)(ws + bfBuf);
    __hip_bfloat16* Walb  = (__hip_bfloat16*)(ws + bfBuf + wBuf);
    __hip_bfloat16* Wxb   = (__hip_bfloat16*)(ws + bfBuf + 2 * wBuf);
    __hip_bfloat16* Woutb = (__hip_bfloat16*)(ws + bfBuf + 3 * wBuf);
    char* rest = ws + bfBuf + 4 * wBuf;
    __hip_bfloat16* xproj = (__hip_bfloat16*)rest;                 // then cell
    unsigned int*   EVb   = (unsigned int*)(rest + bfBuf);         // 67 MB

    __hip_bfloat16* hbuf  = xb;      // x dead after GEMM1
    __hip_bfloat16* cellb = xproj;   // xproj dead after EV GEMM

    dim3 blk(256);
    cvt_f32_bf16<<<dim3(MROWS * Dk / 1024), blk, 0, stream>>>(x, xb, MROWS * Dk);
    cvt_w4<<<dim3(4096), blk, 0, stream>>>(W_in, W_al, W_x, W_out,
                                           Winb, Walb, Wxb, Woutb);

    dim3 grid(1024);
    gemm_bt<0><<<grid, blk, 0, stream>>>(xb, Winb, xproj);
    gemm_ev<<<grid, dim3(512), 0, stream>>>(xproj, Walb, Wxb, b_al, b_v,
                                            (unsigned short*)EVb);
    scan_kernel<<<dim3(128), dim3(64), 0, stream>>>(EVb, h0, d_al, hbuf, hfin);
    gpass<<<dim3(2048), blk, 0, stream>>>(hbuf, cellb, MROWS * Dk);
    gemm_bt<1><<<grid, blk, 0, stream>>>(cellb, Woutb, out);
}